// Round 5
// baseline (59.565 us; speedup 1.0000x reference)
//
#include <hip/hip_runtime.h>
#include <cstdint>

#define IMG_ELEMS 784
#define NIMG_GRP 16
#define WAVES_TOTAL 2048           // 512 blocks x 4 waves; each wave: 2 groups
#define BLOCKS 512

typedef __attribute__((ext_vector_type(8))) short short8;
typedef __attribute__((ext_vector_type(4))) float f32x4;

union ABu { uint32_t u[4]; short8 v; };

__device__ inline uint32_t pk_bf16(float a, float b) {
    uint32_t r;
    asm("v_cvt_pk_bf16_f32 %0, %1, %2" : "=v"(r) : "v"(a), "v"(b));
    return r;  // lo = bf16(a), hi = bf16(b)
}

__global__ __launch_bounds__(256, 2) void fused_digit_regstream_kernel(
    const float* __restrict__ x,
    const float* __restrict__ cw9,
    const float* __restrict__ Wlin,
    const float* __restrict__ bias,
    float* __restrict__ out,
    int ngroups)
{
    const int tid  = threadIdx.x;
    const int lane = tid & 63;
    const int wave = blockIdx.x * 4 + (tid >> 6);
    const int rc = lane & 15;   // A-row (image in group) AND B/D-col (class)
    const int g  = lane >> 4;   // k-subgroup: conv output cols 8g..8g+7

    // uniform conv weights + bias
    float cw[9];
#pragma unroll
    for (int k = 0; k < 9; ++k) cw[k] = cw9[k];
    const float bv = (rc < 10) ? bias[rc] : 0.0f;

    // ---- B fragments (verified layout from R2/R4): one per conv row ----
    ABu bf[26];
#pragma unroll
    for (int c = 0; c < 26; ++c) {
#pragma unroll
        for (int m = 0; m < 4; ++m) {
            const int c0 = 8 * g + 2 * m;
            const int c1 = c0 + 1;
            const bool v0 = (c0 < 26) && (rc < 10);
            const bool v1 = (c1 < 26) && (rc < 10);
            const float w0 = v0 ? Wlin[(c * 26 + c0) * 10 + rc] : 0.0f;
            const float w1 = v1 ? Wlin[(c * 26 + c1) * 10 + rc] : 0.0f;
            bf[c].u[m] = pk_bf16(w0, w1);
        }
    }

    // per-lane column offsets (floats), clamped so g=3 never reads past a row;
    // duplicated data for g=3 feeds only zero B-weights (cols >= 26)
    const int co0 = 8 * g;
    const int co1 = (8 * g + 4 > 24) ? 24 : 8 * g + 4;
    const int co2 = (8 * g + 8 > 24) ? 24 : 8 * g + 8;

#pragma unroll
    for (int gi = 0; gi < 2; ++gi) {
        const int grp = wave + gi * WAVES_TOTAL;
        if (grp >= ngroups) break;

        // this lane streams image rc of the group
        const float* ip = x + ((size_t)grp * NIMG_GRP + rc) * IMG_ELEMS;

        float accr[3][8];
#pragma unroll
        for (int s = 0; s < 3; ++s)
#pragma unroll
            for (int j = 0; j < 8; ++j) accr[s][j] = 0.0f;

        f32x4 acc = {0.f, 0.f, 0.f, 0.f};

        // prefetch input row 0
        float4 n0 = *(const float4*)(ip + co0);
        float4 n1 = *(const float4*)(ip + co1);
        float4 n2 = *(const float4*)(ip + co2);

#pragma unroll
        for (int t = 0; t < 28; ++t) {
            float in[12];
            *(float4*)&in[0] = n0;
            *(float4*)&in[4] = n1;
            *(float4*)&in[8] = n2;
            if (t < 27) {  // prefetch next row while computing this one
                const float* rp = ip + (t + 1) * 28;
                n0 = *(const float4*)(rp + co0);
                n1 = *(const float4*)(rp + co1);
                n2 = *(const float4*)(rp + co2);
            }

            const int s0 = t % 3;            // output row t       (kernel row 0)
            const int s1 = (t + 2) % 3;      // output row t-1     (kernel row 1)
            const int s2 = (t + 1) % 3;      // output row t-2     (kernel row 2)

            if (t <= 25) {
#pragma unroll
                for (int j = 0; j < 8; ++j)
                    accr[s0][j] = fmaf(in[j], cw[0],
                                  fmaf(in[j + 1], cw[1],
                                  fmaf(in[j + 2], cw[2], accr[s0][j])));
            }
            if (t >= 1 && t <= 26) {
#pragma unroll
                for (int j = 0; j < 8; ++j)
                    accr[s1][j] = fmaf(in[j], cw[3],
                                  fmaf(in[j + 1], cw[4],
                                  fmaf(in[j + 2], cw[5], accr[s1][j])));
            }
            if (t >= 2) {
#pragma unroll
                for (int j = 0; j < 8; ++j)
                    accr[s2][j] = fmaf(in[j], cw[6],
                                  fmaf(in[j + 1], cw[7],
                                  fmaf(in[j + 2], cw[8], accr[s2][j])));

                // output row o = t-2 complete: relu -> bf16 A-frag -> MFMA
                const int o = t - 2;
                ABu a;
#pragma unroll
                for (int m = 0; m < 4; ++m)
                    a.u[m] = pk_bf16(fmaxf(accr[s2][2 * m], 0.f),
                                     fmaxf(accr[s2][2 * m + 1], 0.f));
                acc = __builtin_amdgcn_mfma_f32_16x16x32_bf16(a.v, bf[o].v, acc, 0, 0, 0);
#pragma unroll
                for (int j = 0; j < 8; ++j) accr[s2][j] = 0.0f;  // free slot
            }
        }

        // ---- store: D[row=img][col=class], row=(lane>>4)*4+q, col=lane&15 ----
        if (rc < 10) {
            float* po = out + ((size_t)grp * NIMG_GRP + (size_t)g * 4) * 10 + rc;
#pragma unroll
            for (int q = 0; q < 4; ++q) po[q * 10] = acc[q] + bv;
        }
    }
}

extern "C" void kernel_launch(void* const* d_in, const int* in_sizes, int n_in,
                              void* d_out, int out_size, void* d_ws, size_t ws_size,
                              hipStream_t stream) {
    const float* x   = (const float*)d_in[0];
    const float* cw  = (const float*)d_in[1];
    const float* W   = (const float*)d_in[2];
    const float* b   = (const float*)d_in[3];
    float* out = (float*)d_out;

    const int nimg    = in_sizes[0] / IMG_ELEMS;
    const int ngroups = nimg / NIMG_GRP;

    hipLaunchKernelGGL(fused_digit_regstream_kernel, dim3(BLOCKS), dim3(256), 0, stream,
                       x, cw, W, b, out, ngroups);
}

// Round 6
// 46.890 us; speedup vs baseline: 1.2703x; 1.2703x over previous
//
#include <hip/hip_runtime.h>
#include <cstdint>

#define IMG_ELEMS 784
#define NIMG_GRP 16
#define BLOCKS 1024                // 4 blocks/CU x 256 CU; 4096 waves = 4096 groups
#define WFRAG_DW (26 * 64 * 4)     // 6656 dwords = 26,624 B of LDS for W frags

typedef __attribute__((ext_vector_type(8))) short short8;
typedef __attribute__((ext_vector_type(4))) float f32x4;

union ABu { uint32_t u[4]; short8 v; };

__device__ inline uint32_t pk_bf16(float a, float b) {
    uint32_t r;
    asm("v_cvt_pk_bf16_f32 %0, %1, %2" : "=v"(r) : "v"(a), "v"(b));
    return r;  // lo = bf16(a), hi = bf16(b)
}

__global__ __launch_bounds__(256, 4) void fused_digit_regstream_kernel(
    const float* __restrict__ x,
    const float* __restrict__ cw9,
    const float* __restrict__ Wlin,
    const float* __restrict__ bias,
    float* __restrict__ out,
    int ngroups)
{
    __shared__ uint32_t wlds[WFRAG_DW];
    const int tid  = threadIdx.x;
    const int lane = tid & 63;
    const int wave = blockIdx.x * 4 + (tid >> 6);
    const int rc = lane & 15;   // A-row (image in group) AND B/D-col (class)
    const int g  = lane >> 4;   // conv output cols 8g..8g+7

    // uniform conv weights + bias
    float cw[9];
#pragma unroll
    for (int k = 0; k < 9; ++k) cw[k] = cw9[k];
    const float bv = (rc < 10) ? bias[rc] : 0.0f;

    // ---- build W B-fragments in LDS, block-cooperative, once ----
    // frag layout: dword index f = (c*64 + lane)*4 + m  (c = conv row / K-chunk)
    // lane (g,rc), dword m holds bf16 pair W[k=8g+2m][rc], W[k=8g+2m+1][rc]
#pragma unroll
    for (int k = 0; k < 26; ++k) {
        const int f   = k * 256 + tid;
        const int c   = f >> 8;
        const int rem = f & 255;
        const int ln  = rem >> 2;
        const int m   = rem & 3;
        const int gt  = ln >> 4;
        const int rt  = ln & 15;
        const int c0  = 8 * gt + 2 * m;
        const int c1  = c0 + 1;
        const bool v0 = (c0 < 26) && (rt < 10);
        const bool v1 = (c1 < 26) && (rt < 10);
        const float w0 = v0 ? Wlin[(c * 26 + c0) * 10 + rt] : 0.0f;
        const float w1 = v1 ? Wlin[(c * 26 + c1) * 10 + rt] : 0.0f;
        wlds[f] = pk_bf16(w0, w1);
    }
    __syncthreads();
    const short8* wfrag = (const short8*)wlds;

    // per-lane column offsets (floats), clamped so g=3 never reads past a row;
    // duplicate data feeds only zero B-weights (cols >= 26)
    const int co0 = 8 * g;
    const int co1 = (8 * g + 4 > 24) ? 24 : 8 * g + 4;
    const int co2 = (8 * g + 8 > 24) ? 24 : 8 * g + 8;

    for (int grp = wave; grp < ngroups; grp += BLOCKS * 4) {
        // this lane streams image rc of the group
        const float* ip = x + ((size_t)grp * NIMG_GRP + rc) * IMG_ELEMS;

        float accr[3][8];
#pragma unroll
        for (int s = 0; s < 3; ++s)
#pragma unroll
            for (int j = 0; j < 8; ++j) accr[s][j] = 0.0f;

        f32x4 acc = {0.f, 0.f, 0.f, 0.f};

        // 2-deep row pipeline: buf[t%3] holds row t; rows t+1,t+2 in flight
        float buf[3][12];
#pragma unroll
        for (int t = 0; t < 2; ++t) {
            const float* rp = ip + t * 28;
            *(float4*)&buf[t][0] = *(const float4*)(rp + co0);
            *(float4*)&buf[t][4] = *(const float4*)(rp + co1);
            *(float4*)&buf[t][8] = *(const float4*)(rp + co2);
        }

#pragma unroll
        for (int t = 0; t < 28; ++t) {
            if (t + 2 < 28) {  // issue row t+2 loads before computing row t
                const float* rp = ip + (t + 2) * 28;
                *(float4*)&buf[(t + 2) % 3][0] = *(const float4*)(rp + co0);
                *(float4*)&buf[(t + 2) % 3][4] = *(const float4*)(rp + co1);
                *(float4*)&buf[(t + 2) % 3][8] = *(const float4*)(rp + co2);
            }
            const float* in = buf[t % 3];

            const int s0 = t % 3;            // output row t     (kernel row 0)
            const int s1 = (t + 2) % 3;      // output row t-1   (kernel row 1)
            const int s2 = (t + 1) % 3;      // output row t-2   (kernel row 2)

            if (t <= 25) {
#pragma unroll
                for (int j = 0; j < 8; ++j)
                    accr[s0][j] = fmaf(in[j], cw[0],
                                  fmaf(in[j + 1], cw[1],
                                  fmaf(in[j + 2], cw[2], accr[s0][j])));
            }
            if (t >= 1 && t <= 26) {
#pragma unroll
                for (int j = 0; j < 8; ++j)
                    accr[s1][j] = fmaf(in[j], cw[3],
                                  fmaf(in[j + 1], cw[4],
                                  fmaf(in[j + 2], cw[5], accr[s1][j])));
            }
            if (t >= 2) {
#pragma unroll
                for (int j = 0; j < 8; ++j)
                    accr[s2][j] = fmaf(in[j], cw[6],
                                  fmaf(in[j + 1], cw[7],
                                  fmaf(in[j + 2], cw[8], accr[s2][j])));

                // output row o = t-2 complete: relu -> bf16 A-frag -> MFMA
                const int o = t - 2;
                ABu a;
#pragma unroll
                for (int m = 0; m < 4; ++m)
                    a.u[m] = pk_bf16(fmaxf(accr[s2][2 * m], 0.f),
                                     fmaxf(accr[s2][2 * m + 1], 0.f));
                acc = __builtin_amdgcn_mfma_f32_16x16x32_bf16(
                          a.v, wfrag[o * 64 + lane], acc, 0, 0, 0);
#pragma unroll
                for (int j = 0; j < 8; ++j) accr[s2][j] = 0.0f;  // free slot
            }
        }

        // ---- store: D[row=img][col=class], row=(lane>>4)*4+q, col=lane&15 ----
        if (rc < 10) {
            float* po = out + ((size_t)grp * NIMG_GRP + (size_t)g * 4) * 10 + rc;
#pragma unroll
            for (int q = 0; q < 4; ++q) po[q * 10] = acc[q] + bv;
        }
    }
}

extern "C" void kernel_launch(void* const* d_in, const int* in_sizes, int n_in,
                              void* d_out, int out_size, void* d_ws, size_t ws_size,
                              hipStream_t stream) {
    const float* x   = (const float*)d_in[0];
    const float* cw  = (const float*)d_in[1];
    const float* W   = (const float*)d_in[2];
    const float* b   = (const float*)d_in[3];
    float* out = (float*)d_out;

    const int nimg    = in_sizes[0] / IMG_ELEMS;
    const int ngroups = nimg / NIMG_GRP;

    hipLaunchKernelGGL(fused_digit_regstream_kernel, dim3(BLOCKS), dim3(256), 0, stream,
                       x, cw, W, b, out, ngroups);
}

// Round 7
// 45.795 us; speedup vs baseline: 1.3007x; 1.0239x over previous
//
#include <hip/hip_runtime.h>
#include <cstdint>

#define IMG_ELEMS 784
#define NIMG_GRP 16
#define IMG_STRIDE_DW 788                    // 197*4 dwords: 16B-aligned, odd superbank
#define STAGE_DW (NIMG_GRP * IMG_STRIDE_DW)  // 12,608 dw = 50,432 B
#define SCRATCH_DW 2048                      // dbuf: 2 x (4 waves x 64 lanes x 4 f32)
#define BLOCKS 512                           // 2 blocks/CU x 256 CU

typedef __attribute__((ext_vector_type(8))) short short8;
typedef __attribute__((ext_vector_type(4))) float f32x4;

union ABu { uint32_t u[4]; short8 v; };

typedef const __attribute__((address_space(1))) void* gp1_t;
typedef __attribute__((address_space(3))) void* lp3_t;

__device__ inline uint32_t pk_bf16(float a, float b) {
    uint32_t r;
    asm("v_cvt_pk_bf16_f32 %0, %1, %2" : "=v"(r) : "v"(a), "v"(b));
    return r;  // lo = bf16(a), hi = bf16(b)
}

// wave `widb` DMA-stages its 4 images of group `grp` into LDS (f32, coalesced)
__device__ inline void stage_group(const float* __restrict__ x, float* stage,
                                   int grp, int widb, int lane) {
    const float* gsrc = x + (size_t)grp * (NIMG_GRP * IMG_ELEMS);
#pragma unroll
    for (int k = 0; k < 4; ++k) {
        const int im = widb * 4 + k;
        const float* s = gsrc + im * IMG_ELEMS;
        float* dbase = stage + im * IMG_STRIDE_DW;
#pragma unroll
        for (int j = 0; j < 3; ++j) {   // floats [256j, 256j+256)
            __builtin_amdgcn_global_load_lds((gp1_t)(s + j * 256 + lane * 4),
                                             (lp3_t)(dbase + j * 256), 16, 0, 0);
        }
        if (lane < 4) {                 // tail floats 768..783
            __builtin_amdgcn_global_load_lds((gp1_t)(s + 768 + lane * 4),
                                             (lp3_t)(dbase + 768), 16, 0, 0);
        }
    }
}

__global__ __launch_bounds__(256, 2) void fused_digit_dma_kernel(
    const float* __restrict__ x,
    const float* __restrict__ cw9,
    const float* __restrict__ Wlin,
    const float* __restrict__ bias,
    float* __restrict__ out,
    int ngroups, int grp_per_blk)
{
    __shared__ float smem[STAGE_DW + SCRATCH_DW];
    float* stagebuf = smem;

    const int tid  = threadIdx.x;
    const int lane = tid & 63;
    const int widb = tid >> 6;
    const int rc = lane & 15;   // A-row (image) AND D-col (class)
    const int g  = lane >> 4;   // conv output cols 8g..8g+7

    // uniform conv weights + bias
    float cw[9];
#pragma unroll
    for (int k = 0; k < 9; ++k) cw[k] = cw9[k];
    const float bv = (rc < 10) ? bias[rc] : 0.0f;

    // K-split: wave widb owns conv output rows [R0, R0+RC)
    const int R0 = (widb < 2) ? widb * 7 : 14 + (widb - 2) * 6;  // 0,7,14,20
    const int RC = (widb < 2) ? 7 : 6;

    // W B-fragments for this wave's rows (28 VGPRs)
    ABu bf[7];
#pragma unroll
    for (int rr = 0; rr < 7; ++rr) {
        const int r = R0 + rr;
#pragma unroll
        for (int m = 0; m < 4; ++m) {
            const int c0 = 8 * g + 2 * m;
            const int c1 = c0 + 1;
            const bool v0 = (rr < RC) && (c0 < 26) && (rc < 10);
            const bool v1 = (rr < RC) && (c1 < 26) && (rc < 10);
            const float w0 = v0 ? Wlin[(r * 26 + c0) * 10 + rc] : 0.0f;
            const float w1 = v1 ? Wlin[(r * 26 + c1) * 10 + rc] : 0.0f;
            bf[rr].u[m] = pk_bf16(w0, w1);
        }
    }

    // per-lane col offsets (floats), clamped; dup data hits zero B-weights
    const int co0 = 8 * g;
    const int co1 = (8 * g + 4 > 24) ? 24 : 8 * g + 4;
    const int co2 = (8 * g + 8 > 24) ? 24 : 8 * g + 8;

    const int gstart = blockIdx.x * grp_per_blk;

    // prologue: stage first group
    if (gstart < ngroups) stage_group(x, stagebuf, gstart, widb, lane);

    for (int i = 0; i < grp_per_blk; ++i) {
        const int grp = gstart + i;
        if (grp >= ngroups) break;   // block-uniform

        asm volatile("s_waitcnt vmcnt(0)" ::: "memory");  // own DMA done
        __syncthreads();                                  // everyone's DMA done

        // ---- conv rows [R0, R0+RC) of image rc, cols 8g..8g+7, f32 ----
        const float* ib = &stagebuf[rc * IMG_STRIDE_DW];
        float accr[3][8];
#pragma unroll
        for (int s = 0; s < 3; ++s)
#pragma unroll
            for (int j = 0; j < 8; ++j) accr[s][j] = 0.0f;
        f32x4 acc = {0.f, 0.f, 0.f, 0.f};

#pragma unroll
        for (int t = 0; t < 9; ++t) {          // input rows R0+t
            if (t < RC + 2) {
                const float* rp = ib + (R0 + t) * 28;
                float in[12];
                *(float4*)&in[0] = *(const float4*)(rp + co0);
                *(float4*)&in[4] = *(const float4*)(rp + co1);
                *(float4*)&in[8] = *(const float4*)(rp + co2);

                const int s0 = t % 3;          // out row t   (kernel row 0)
                const int s1 = (t + 2) % 3;    // out row t-1 (kernel row 1)
                const int s2 = (t + 1) % 3;    // out row t-2 (kernel row 2)

                if (t < RC) {
#pragma unroll
                    for (int j = 0; j < 8; ++j)
                        accr[s0][j] = fmaf(in[j], cw[0],
                                      fmaf(in[j + 1], cw[1],
                                      fmaf(in[j + 2], cw[2], accr[s0][j])));
                }
                if (t >= 1 && t <= RC) {
#pragma unroll
                    for (int j = 0; j < 8; ++j)
                        accr[s1][j] = fmaf(in[j], cw[3],
                                      fmaf(in[j + 1], cw[4],
                                      fmaf(in[j + 2], cw[5], accr[s1][j])));
                }
                if (t >= 2) {
#pragma unroll
                    for (int j = 0; j < 8; ++j)
                        accr[s2][j] = fmaf(in[j], cw[6],
                                      fmaf(in[j + 1], cw[7],
                                      fmaf(in[j + 2], cw[8], accr[s2][j])));
                    // local output row o = t-2 complete
                    ABu a;
#pragma unroll
                    for (int m = 0; m < 4; ++m)
                        a.u[m] = pk_bf16(fmaxf(accr[s2][2 * m], 0.f),
                                         fmaxf(accr[s2][2 * m + 1], 0.f));
                    acc = __builtin_amdgcn_mfma_f32_16x16x32_bf16(
                              a.v, bf[t - 2].v, acc, 0, 0, 0);
#pragma unroll
                    for (int j = 0; j < 8; ++j) accr[s2][j] = 0.0f;
                }
            }
        }

        // ---- cross-wave K-reduction (double-buffered scratch) ----
        float* sc = &smem[STAGE_DW + (i & 1) * 1024];
        *reinterpret_cast<f32x4*>(sc + widb * 256 + lane * 4) = acc;
        __syncthreads();   // conv reads done + scratch visible

        // buffer free: start next group's DMA immediately (overlaps reduce)
        if (i + 1 < grp_per_blk && grp + 1 < ngroups)
            stage_group(x, stagebuf, grp + 1, widb, lane);

        if (widb == 0) {
            const float* scr = sc + lane * 4;
            f32x4 s0 = *reinterpret_cast<const f32x4*>(scr);
            f32x4 s1 = *reinterpret_cast<const f32x4*>(scr + 256);
            f32x4 s2 = *reinterpret_cast<const f32x4*>(scr + 512);
            f32x4 s3 = *reinterpret_cast<const f32x4*>(scr + 768);
            if (rc < 10) {
                float* po = out + ((size_t)grp * NIMG_GRP + (size_t)g * 4) * 10 + rc;
#pragma unroll
                for (int q = 0; q < 4; ++q)
                    po[q * 10] = s0[q] + s1[q] + s2[q] + s3[q] + bv;
            }
        }
    }
}

extern "C" void kernel_launch(void* const* d_in, const int* in_sizes, int n_in,
                              void* d_out, int out_size, void* d_ws, size_t ws_size,
                              hipStream_t stream) {
    const float* x   = (const float*)d_in[0];
    const float* cw  = (const float*)d_in[1];
    const float* W   = (const float*)d_in[2];
    const float* b   = (const float*)d_in[3];
    float* out = (float*)d_out;

    const int nimg    = in_sizes[0] / IMG_ELEMS;
    const int ngroups = nimg / NIMG_GRP;
    const int gpb     = (ngroups + BLOCKS - 1) / BLOCKS;  // 8 for B=65536

    hipLaunchKernelGGL(fused_digit_dma_kernel, dim3(BLOCKS), dim3(256), 0, stream,
                       x, cw, W, b, out, ngroups, gpb);
}